// Round 6
// baseline (631.144 us; speedup 1.0000x reference)
//
#include <hip/hip_runtime.h>

typedef __attribute__((ext_vector_type(4))) float f32x4;
typedef __attribute__((ext_vector_type(8))) short s16x8;
typedef unsigned int u32;

#define XDIM 440
#define ODIM 220

// ---------- packed split helpers (fp32 -> bf16hi|bf16lo in one u32) ----------
__device__ __forceinline__ u32 cvtpk(float a, float b){
    u32 r; asm("v_cvt_pk_bf16_f32 %0, %1, %2" : "=v"(r) : "v"(a), "v"(b)); return r;
}
__device__ __forceinline__ u32 permb(u32 a, u32 b, u32 s){ return __builtin_amdgcn_perm(a, b, s); }

__device__ __forceinline__ u32 packf(float v){
    u32 h = cvtpk(v, v);                                  // [15:0] = bf16(v)
    float hf = __builtin_bit_cast(float, h << 16);
    u32 lo = cvtpk(v - hf, v - hf);                       // v-hf exact (Sterbenz)
    return permb(h, lo, 0x05040100u);                     // [31:16]=hi [15:0]=lo
}

__device__ __forceinline__ void split8pk(const float* v, s16x8& h, s16x8& l){
    uint4 hu, lu; u32* hp = (u32*)&hu; u32* lp = (u32*)&lu;
    #pragma unroll
    for (int j = 0; j < 4; ++j){
        u32 hk = cvtpk(v[2*j], v[2*j+1]);
        float h0 = __builtin_bit_cast(float, hk << 16);
        float h1 = __builtin_bit_cast(float, hk & 0xFFFF0000u);
        lp[j] = cvtpk(v[2*j] - h0, v[2*j+1] - h1);
        hp[j] = hk;
    }
    h = __builtin_bit_cast(s16x8, hu);
    l = __builtin_bit_cast(s16x8, lu);
}

// 8 packed u32 -> (hi, lo) s16x8 fragments, 1 v_perm per output reg
__device__ __forceinline__ void buildfrag(const u32* p, s16x8& h, s16x8& l){
    uint4 U0 = *(const uint4*)p;
    uint4 U1 = *(const uint4*)(p + 4);
    u32 u0=U0.x,u1=U0.y,u2=U0.z,u3=U0.w,u4=U1.x,u5=U1.y,u6=U1.z,u7=U1.w;
    uint4 hu, lu;
    hu.x = permb(u1,u0,0x07060302u); lu.x = permb(u1,u0,0x05040100u);
    hu.y = permb(u3,u2,0x07060302u); lu.y = permb(u3,u2,0x05040100u);
    hu.z = permb(u5,u4,0x07060302u); lu.z = permb(u5,u4,0x05040100u);
    hu.w = permb(u7,u6,0x07060302u); lu.w = permb(u7,u6,0x05040100u);
    h = __builtin_bit_cast(s16x8, hu);
    l = __builtin_bit_cast(s16x8, lu);
}

__device__ __forceinline__ s16x8 ld8u(const unsigned short* p){ return *(const s16x8*)p; }

// D += A*B, split-bf16: AhBh + AhBl + AlBh (AlBl dropped, ~2^-18)
__device__ __forceinline__ f32x4 mm3(s16x8 ah, s16x8 al, s16x8 bh, s16x8 bl, f32x4 c){
    c = __builtin_amdgcn_mfma_f32_16x16x32_bf16(ah, bh, c, 0, 0, 0);
    c = __builtin_amdgcn_mfma_f32_16x16x32_bf16(ah, bl, c, 0, 0, 0);
    c = __builtin_amdgcn_mfma_f32_16x16x32_bf16(al, bh, c, 0, 0, 0);
    return c;
}

// ---------- weight prep: split to bf16 hi/lo, pad to [240][64] ----------
// rows: [0..47]=bW1 [48..95]=bW2 [96..111]=bW3 [112..159]=sW1 [160..207]=sW2 [208..239]=sW3
__device__ __forceinline__ unsigned short bf_rne(float f){
    unsigned u = __builtin_bit_cast(unsigned, f);
    return (unsigned short)((u + 0x7FFFu + ((u >> 16) & 1u)) >> 16);
}

__global__ void prep_w(const float* __restrict__ bW1, const float* __restrict__ bW2,
                       const float* __restrict__ bW3, const float* __restrict__ sW1,
                       const float* __restrict__ sW2, const float* __restrict__ sW3,
                       const float* __restrict__ bb1, const float* __restrict__ bb2,
                       const float* __restrict__ bb3, const float* __restrict__ sb1,
                       const float* __restrict__ sb2, const float* __restrict__ sb3,
                       unsigned short* __restrict__ WH, unsigned short* __restrict__ WL,
                       float* __restrict__ BIAS)
{
    int i = blockIdx.x * 256 + threadIdx.x;
    if (i < 15360) {
        int n = i >> 6, k = i & 63;
        float w = 0.f;
        if      (n < 48)  { int r = n;     if (r < 40 && k < 40) w = bW1[r*40+k]; }
        else if (n < 96)  { int r = n-48;  if (r < 40 && k < 40) w = bW2[r*40+k]; }
        else if (n < 112) { int r = n-96;  if (r < 10 && k < 40) w = bW3[r*40+k]; }
        else if (n < 160) { int r = n-112; if (r < 41 && k < 41) w = sW1[r*41+k]; }
        else if (n < 208) { int r = n-160; if (r < 41 && k < 41) w = sW2[r*41+k]; }
        else              { int r = n-208; if (r < 22 && k < 41) w = sW3[r*41+k]; }
        unsigned short h = bf_rne(w);
        float hf = __builtin_bit_cast(float, ((unsigned)h) << 16);
        WH[i] = h; WL[i] = bf_rne(w - hf);
    } else if (i < 15600) {
        int n = i - 15360;
        float b;
        if      (n < 48)  b = (n     < 40) ? bb1[n]     : 0.f;
        else if (n < 96)  b = (n-48  < 40) ? bb2[n-48]  : 0.f;
        else if (n < 112) b = (n-96  < 10) ? bb3[n-96]  : -1e30f;
        else if (n < 160) b = (n-112 < 41) ? sb1[n-112] : 0.f;
        else if (n < 208) b = (n-160 < 41) ? sb2[n-160] : 0.f;
        else              b = (n-208 < 22) ? sb3[n-208] : -1e30f;
        BIAS[n] = b;
    }
}

// ================= kernel 1: big net -> iaS (slot-major [10][nrow]) =================
__global__ __launch_bounds__(64, 4) void big_net(
    const float* __restrict__ x,
    const unsigned short* __restrict__ WH, const unsigned short* __restrict__ WL,
    const float* __restrict__ BIAS, float* __restrict__ iaS, int nrow)
{
    __shared__ u32 Act[32][68];
    const int l = threadIdx.x, q = l >> 4, li = l & 15;
    const int R0 = blockIdx.x * 32;

    for (int f = l; f < 32*20; f += 64) Act[f/20][48 + f%20] = 0u;
    __syncthreads();

    // ---- L1 direct from x (cols 0..63; k>=40 hits zero weights) ----
    #pragma unroll
    for (int t = 0; t < 2; ++t){
        const float* xp = x + (size_t)(R0 + t*16 + li) * XDIM;
        float a0[8], a1[8];
        *(float4*)(a0)   = *(const float4*)(xp + q*8);
        *(float4*)(a0+4) = *(const float4*)(xp + q*8 + 4);
        *(float4*)(a1)   = *(const float4*)(xp + 32 + q*8);
        *(float4*)(a1+4) = *(const float4*)(xp + 32 + q*8 + 4);
        s16x8 ah0,al0,ah1,al1;
        split8pk(a0, ah0, al0); split8pk(a1, ah1, al1);
        #pragma unroll
        for (int nt = 0; nt < 3; ++nt){
            int n = nt*16 + li;
            float b = BIAS[n];
            f32x4 acc = {b,b,b,b};
            acc = mm3(ah0,al0, ld8u(WH + n*64 + q*8),      ld8u(WL + n*64 + q*8),      acc);
            acc = mm3(ah1,al1, ld8u(WH + n*64 + 32 + q*8), ld8u(WL + n*64 + 32 + q*8), acc);
            #pragma unroll
            for (int r = 0; r < 4; ++r)
                Act[t*16 + q*4 + r][nt*16 + li] = packf(fmaxf(acc[r], 0.f));
        }
    }
    __syncthreads();

    // ---- L2: Act -> Act ----
    #pragma unroll
    for (int t = 0; t < 2; ++t){
        s16x8 ah0,al0,ah1,al1;
        const u32* ap = &Act[t*16 + li][0];
        buildfrag(ap + q*8, ah0, al0);
        buildfrag(ap + 32 + q*8, ah1, al1);
        #pragma unroll
        for (int nt = 0; nt < 3; ++nt){
            int n = 48 + nt*16 + li;
            float b = BIAS[n];
            f32x4 acc = {b,b,b,b};
            acc = mm3(ah0,al0, ld8u(WH + n*64 + q*8),      ld8u(WL + n*64 + q*8),      acc);
            acc = mm3(ah1,al1, ld8u(WH + n*64 + 32 + q*8), ld8u(WL + n*64 + 32 + q*8), acc);
            #pragma unroll
            for (int r = 0; r < 4; ++r)
                Act[t*16 + q*4 + r][nt*16 + li] = packf(fmaxf(acc[r], 0.f));
        }
    }
    __syncthreads();

    // ---- L3 + softmax -> iaS ----
    #pragma unroll
    for (int t = 0; t < 2; ++t){
        s16x8 ah0,al0,ah1,al1;
        const u32* ap = &Act[t*16 + li][0];
        buildfrag(ap + q*8, ah0, al0);
        buildfrag(ap + 32 + q*8, ah1, al1);
        int n = 96 + li;
        float b = BIAS[n];
        f32x4 acc = {b,b,b,b};
        acc = mm3(ah0,al0, ld8u(WH + n*64 + q*8),      ld8u(WL + n*64 + q*8),      acc);
        acc = mm3(ah1,al1, ld8u(WH + n*64 + 32 + q*8), ld8u(WL + n*64 + 32 + q*8), acc);
        #pragma unroll
        for (int r = 0; r < 4; ++r){
            float v = acc[r];
            float m = v;
            m = fmaxf(m, __shfl_xor(m,1)); m = fmaxf(m, __shfl_xor(m,2));
            m = fmaxf(m, __shfl_xor(m,4)); m = fmaxf(m, __shfl_xor(m,8));
            float e = __expf(v - m);
            float sum = e;
            sum += __shfl_xor(sum,1); sum += __shfl_xor(sum,2);
            sum += __shfl_xor(sum,4); sum += __shfl_xor(sum,8);
            if (li < 10)
                iaS[(size_t)li * nrow + R0 + t*16 + q*4 + r] = __fdividef(e, sum);
        }
    }
}

// ================= kernel 2: small net, one (32-row, slot) per 1-wave block =================
__global__ __launch_bounds__(64, 4) void small_net(
    const float* __restrict__ x,
    const unsigned short* __restrict__ WH, const unsigned short* __restrict__ WL,
    const float* __restrict__ BIAS, const float* __restrict__ iaS,
    float* __restrict__ out, int nrow)
{
    __shared__ u32 xsl[33][44];     // packed split inputs, stride 44 (+1 guard row)
    __shared__ u32 Act[32][68];     // packed split activations / float out-staging

    const int l = threadIdx.x, q = l >> 4, li = l & 15;
    const int bid = blockIdx.x;
    const int s  = bid % 10;        // slot fast: 10 slot-blocks of same rows adjacent
    const int R0 = (bid / 10) * 32;

    // zero pads: guard row + Act cols 48..67
    if (l < 44) xsl[32][l] = 0u;
    for (int f = l; f < 32*20; f += 64) Act[f/20][48 + f%20] = 0u;

    // ---- stage slot chunk (coalesced) + iab, pre-split packed ----
    const float* xs = x + 40 + s*40;
    #pragma unroll
    for (int it = 0; it < 5; ++it){
        int f = l + 64*it;                 // 0..319
        int r = f / 10, c = f - r*10;
        float4 v = *(const float4*)(xs + (size_t)(R0 + r) * XDIM + 4*c);
        uint4 pk;
        pk.x = packf(v.x); pk.y = packf(v.y); pk.z = packf(v.z); pk.w = packf(v.w);
        *(uint4*)&xsl[r][4*c] = pk;
    }
    if (l < 32){
        uint4 pk;
        pk.x = packf(iaS[(size_t)s * nrow + R0 + l]);
        pk.y = 0u; pk.z = 0u; pk.w = 0u;
        *(uint4*)&xsl[l][40] = pk;         // k=40 = iab, k=41..43 = 0
    }
    __syncthreads();

    // ---- L1: xsl -> Act ----
    #pragma unroll
    for (int t = 0; t < 2; ++t){
        s16x8 ah0,al0,ah1,al1;
        const u32* xr = &xsl[t*16 + li][0];
        buildfrag(xr + q*8, ah0, al0);
        buildfrag(xr + 32 + q*8, ah1, al1);    // k 40..63: iab + zeros/garbage x zero-weights
        #pragma unroll
        for (int nt = 0; nt < 3; ++nt){
            int n = 112 + nt*16 + li;
            float b = BIAS[n];
            f32x4 acc = {b,b,b,b};
            acc = mm3(ah0,al0, ld8u(WH + n*64 + q*8),      ld8u(WL + n*64 + q*8),      acc);
            acc = mm3(ah1,al1, ld8u(WH + n*64 + 32 + q*8), ld8u(WL + n*64 + 32 + q*8), acc);
            #pragma unroll
            for (int r = 0; r < 4; ++r)
                Act[t*16 + q*4 + r][nt*16 + li] = packf(fmaxf(acc[r], 0.f));
        }
    }
    __syncthreads();

    // ---- L2: Act -> Act ----
    #pragma unroll
    for (int t = 0; t < 2; ++t){
        s16x8 ah0,al0,ah1,al1;
        const u32* ap = &Act[t*16 + li][0];
        buildfrag(ap + q*8, ah0, al0);
        buildfrag(ap + 32 + q*8, ah1, al1);
        #pragma unroll
        for (int nt = 0; nt < 3; ++nt){
            int n = 160 + nt*16 + li;
            float b = BIAS[n];
            f32x4 acc = {b,b,b,b};
            acc = mm3(ah0,al0, ld8u(WH + n*64 + q*8),      ld8u(WL + n*64 + q*8),      acc);
            acc = mm3(ah1,al1, ld8u(WH + n*64 + 32 + q*8), ld8u(WL + n*64 + 32 + q*8), acc);
            #pragma unroll
            for (int r = 0; r < 4; ++r)
                Act[t*16 + q*4 + r][nt*16 + li] = packf(fmaxf(acc[r], 0.f));
        }
    }
    __syncthreads();

    // ---- L3 + softmax*iab -> float staging in Act cols 0..21 ----
    float* Actf = (float*)&Act[0][0];
    #pragma unroll
    for (int t = 0; t < 2; ++t){
        s16x8 ah0,al0,ah1,al1;
        const u32* ap = &Act[t*16 + li][0];
        buildfrag(ap + q*8, ah0, al0);
        buildfrag(ap + 32 + q*8, ah1, al1);
        int n6 = 208 + li, n7 = 224 + li;
        float b6 = BIAS[n6], b7 = BIAS[n7];
        f32x4 a6 = {b6,b6,b6,b6}, a7 = {b7,b7,b7,b7};
        a6 = mm3(ah0,al0, ld8u(WH + n6*64 + q*8),      ld8u(WL + n6*64 + q*8),      a6);
        a6 = mm3(ah1,al1, ld8u(WH + n6*64 + 32 + q*8), ld8u(WL + n6*64 + 32 + q*8), a6);
        a7 = mm3(ah0,al0, ld8u(WH + n7*64 + q*8),      ld8u(WL + n7*64 + q*8),      a7);
        a7 = mm3(ah1,al1, ld8u(WH + n7*64 + 32 + q*8), ld8u(WL + n7*64 + 32 + q*8), a7);
        #pragma unroll
        for (int r = 0; r < 4; ++r){
            int lr = t*16 + q*4 + r;
            float v0 = a6[r], v1 = a7[r];
            float m = fmaxf(v0, v1);
            m = fmaxf(m, __shfl_xor(m,1)); m = fmaxf(m, __shfl_xor(m,2));
            m = fmaxf(m, __shfl_xor(m,4)); m = fmaxf(m, __shfl_xor(m,8));
            float e0 = __expf(v0 - m), e1 = __expf(v1 - m);
            float sum = e0 + e1;
            sum += __shfl_xor(sum,1); sum += __shfl_xor(sum,2);
            sum += __shfl_xor(sum,4); sum += __shfl_xor(sum,8);
            u32 pk = xsl[lr][40];                              // packed iab
            float iv = __builtin_bit_cast(float, pk & 0xFFFF0000u)
                     + __builtin_bit_cast(float, pk << 16);
            float sc = __fdividef(iv, sum);
            Actf[lr*68 + li] = e0 * sc;
            if (li < 6) Actf[lr*68 + 16 + li] = e1 * sc;
        }
    }
    __syncthreads();

    // ---- cooperative out write: 32 rows x 22 floats ----
    #pragma unroll
    for (int it = 0; it < 11; ++it){
        int f = l + 64*it;                  // 0..703
        int r = f / 22, c = f - r*22;
        out[(size_t)(R0 + r) * ODIM + s*22 + c] = Actf[r*68 + c];
    }
}

extern "C" void kernel_launch(void* const* d_in, const int* in_sizes, int n_in,
                              void* d_out, int out_size, void* d_ws, size_t ws_size,
                              hipStream_t stream)
{
    (void)n_in; (void)out_size; (void)ws_size;
    const float* x   = (const float*)d_in[0];
    const float* bW1 = (const float*)d_in[1];
    const float* bb1 = (const float*)d_in[2];
    const float* bW2 = (const float*)d_in[3];
    const float* bb2 = (const float*)d_in[4];
    const float* bW3 = (const float*)d_in[5];
    const float* bb3 = (const float*)d_in[6];
    const float* sW1 = (const float*)d_in[7];
    const float* sb1 = (const float*)d_in[8];
    const float* sW2 = (const float*)d_in[9];
    const float* sb2 = (const float*)d_in[10];
    const float* sW3 = (const float*)d_in[11];
    const float* sb3 = (const float*)d_in[12];
    float* outp = (float*)d_out;

    unsigned short* WH = (unsigned short*)d_ws;        // 15360 ush
    unsigned short* WL = WH + 15360;                   // 15360 ush
    float* BIAS = (float*)(WH + 30720);                // 240 f
    float* iaS  = (float*)((char*)d_ws + 62464);       // [10][nrow] floats

    const int rows = in_sizes[0] / XDIM;               // 262144

    prep_w<<<61, 256, 0, stream>>>(bW1, bW2, bW3, sW1, sW2, sW3,
                                   bb1, bb2, bb3, sb1, sb2, sb3, WH, WL, BIAS);
    big_net<<<rows/32, 64, 0, stream>>>(x, WH, WL, BIAS, iaS, rows);
    small_net<<<(rows/32)*10, 64, 0, stream>>>(x, WH, WL, BIAS, iaS, outp, rows);
}